// Round 10
// baseline (210.744 us; speedup 1.0000x reference)
//
#include <hip/hip_runtime.h>

#define BB 4
#define NN 16384
#define SS 4096
#define CIN 256
#define COUT 256

#define SC 8                  // s-chunks per knn block pass
#define SCS (SS / SC)         // 512 candidates staged per knn block
#define SUBS 16               // value-dump granularity: 16 subs of 256
#define SUBL 256
#define NPT 4                 // queries per thread (1 ds_read feeds 4 queries)
#define KNNB ((NN / 1024) * SC * BB)           // 16*8*4 = 512 knn blocks
#define GEMMB ((COUT / 128) * (SS / 64) * BB)  // 2*64*4 = 512 gemm blocks
#define RSLVB (BB * NN / 64)                   // 1024 resolve blocks (64 q each)
// grid = 1024 = exactly 4 blocks/CU (2 knn + 2 gemm each), all co-resident.
// k_fused is LDS-throughput-bound (r9 accounting: 196K cy/CU matched 85.5us);
// NPT=4 + 4sx8o micro cut LDS to ~123K cy/CU.

typedef float v2f __attribute__((ext_vector_type(2)));
typedef float v4f __attribute__((ext_vector_type(4)));

__device__ __forceinline__ unsigned short f2bf(float f) {   // RNE float->bf16
    unsigned u = __float_as_uint(f);
    u += 0x7FFF + ((u >> 16) & 1);
    return (unsigned short)(u >> 16);
}
__device__ __forceinline__ float bf2f(unsigned short h) {
    return __uint_as_float((unsigned)h << 16);
}

// Value-only exact top-3 insert (sorted invariant a<=b<=c): 3 full-rate ops.
__device__ __forceinline__ void ins_v(float e, float& a, float& b, float& c) {
    float n1 = __builtin_amdgcn_fmed3f(e, a, b);
    float n2 = __builtin_amdgcn_fmed3f(e, b, c);
    a = fminf(a, e); b = n1; c = n2;
}

// Exact stable top-3 insert, value + index, strict '<' (requires ascending-
// index processing order). Proven passing rounds 3/5/6/7/8/9.
__device__ __forceinline__ void insert_vi(float e, int gi,
                                          float& k0, float& k1, float& k2,
                                          int& i0, int& i1, int& i2) {
    bool c0 = e < k0, c1 = e < k1, c2 = e < k2;
    float n0 = fminf(e, k0);
    float n1 = __builtin_amdgcn_fmed3f(e, k0, k1);
    float n2 = __builtin_amdgcn_fmed3f(e, k1, k2);
    int t1 = c0 ? i0 : gi;
    int t2 = c1 ? i1 : gi;
    i0 = c0 ? gi : i0;
    i1 = c1 ? t1 : i1;
    i2 = c2 ? t2 : i2;
    k0 = n0; k1 = n1; k2 = n2;
}

// Lexicographic (value, index) insert: order-independent exact stable top-3.
// Used only on the <=16 gathered finalists per query. Proven rounds 7/8/9.
__device__ __forceinline__ void ins_lex(float e, int gi,
                                        float& k0, float& k1, float& k2,
                                        int& i0, int& i1, int& i2) {
    bool c0 = (e < k0) || (e == k0 && gi < i0);
    bool c1 = (e < k1) || (e == k1 && gi < i1);
    bool c2 = (e < k2) || (e == k2 && gi < i2);
    float n0 = fminf(e, k0);
    float n1 = __builtin_amdgcn_fmed3f(e, k0, k1);
    float n2 = __builtin_amdgcn_fmed3f(e, k1, k2);
    int t1 = c0 ? i0 : gi;
    int t2 = c1 ? i1 : gi;
    i0 = c0 ? gi : i0;
    i1 = c1 ? t1 : i1;
    i2 = c2 ? t2 : i2;
    k0 = n0; k1 = n1; k2 = n2;
}

// popcount of mask bits strictly below this lane
__device__ __forceinline__ int ltc(unsigned long long m) {
    return __builtin_amdgcn_mbcnt_hi(
        (unsigned)(m >> 32), __builtin_amdgcn_mbcnt_lo((unsigned)m, 0));
}

// v_pk_fma_f32 packed distance: lo/hi = two queries; candidate coords
// broadcast via op_sel. IEEE f32 fma per half, z->y->x nesting:
//   e = x*X + (y*Y + (z*Z + w))
#define E2_FROM(p_xy, p_zw, XX, YY, ZZ, e2)                                    \
    do {                                                                       \
        asm("v_pk_fma_f32 %0, %1, %2, %3 op_sel:[0,0,1] op_sel_hi:[0,1,1]"     \
            : "=v"(e2) : "v"(p_zw), "v"(ZZ), "v"(p_zw));                       \
        asm("v_pk_fma_f32 %0, %1, %2, %0 op_sel:[1,0,0] op_sel_hi:[1,1,1]"     \
            : "+v"(e2) : "v"(p_xy), "v"(YY));                                  \
        asm("v_pk_fma_f32 %0, %1, %2, %0 op_sel:[0,0,0] op_sel_hi:[0,1,1]"     \
            : "+v"(e2) : "v"(p_xy), "v"(XX));                                  \
    } while (0)

#define PK_LO(acc, ap, bw)                                                     \
    asm("v_pk_fma_f32 %0, %1, %2, %0 op_sel:[0,0,0] op_sel_hi:[0,1,1]"         \
        : "+v"(acc) : "v"(ap), "v"(bw))
#define PK_HI(acc, ap, bw)                                                     \
    asm("v_pk_fma_f32 %0, %1, %2, %0 op_sel:[1,0,0] op_sel_hi:[1,1,1]"         \
        : "+v"(acc) : "v"(ap), "v"(bw))

// ---------------------------------------------------------------------------
// knn phase NPT=4: one ds_read_b128 feeds 4 queries (halves knn LDS traffic;
// k_fused is LDS-pipe-bound). Per iter: 1 read + 6 pk_fma + 12 min/med3,
// 4 independent 3-op chains. Value-only screen per 256-sub, bitwise
// identical e and pv to the round-5..9 proven kernel. nb==0 blocks dump
// the staged chunk to cand4.
// ---------------------------------------------------------------------------
__device__ __forceinline__ void knn_phase(int id, int t, float* smem,
                                          const float* __restrict__ xyz1,
                                          const float* __restrict__ xyz2,
                                          float* __restrict__ pv,
                                          float4* __restrict__ cand4) {
    int nb = id & 15;
    int ch = (id >> 4) & 7;
    int b  = id >> 7;
    int s0 = ch * SCS;

    float4* smv = (float4*)smem;
    const float* x2 = xyz2 + (size_t)b * 3 * SS;
    for (int i = t; i < SCS; i += 256) {
        float px = x2[s0 + i];
        float py = x2[SS + s0 + i];
        float pz = x2[2 * SS + s0 + i];
        float4 p4 = make_float4(px, py, pz, fmaf(px, px, fmaf(py, py, pz * pz)));
        smv[i] = p4;
        if (nb == 0) cand4[(size_t)b * SS + s0 + i] = p4;   // 32 dump blocks
    }
    __syncthreads();

    int n0 = nb * 1024 + t;            // queries n0 + {0,256,512,768}
    const float* xb = xyz1 + (size_t)b * 3 * NN;
    float qx[NPT], qy[NPT], qz[NPT];
#pragma unroll
    for (int q = 0; q < NPT; ++q) {
        qx[q] = xb[n0 + q * 256];
        qy[q] = xb[NN + n0 + q * 256];
        qz[q] = xb[2 * NN + n0 + q * 256];
    }
    v2f XXa = {-2.0f * qx[0], -2.0f * qx[1]};
    v2f YYa = {-2.0f * qy[0], -2.0f * qy[1]};
    v2f ZZa = {-2.0f * qz[0], -2.0f * qz[1]};
    v2f XXb = {-2.0f * qx[2], -2.0f * qx[3]};
    v2f YYb = {-2.0f * qy[2], -2.0f * qy[3]};
    v2f ZZb = {-2.0f * qz[2], -2.0f * qz[3]};

#pragma unroll
    for (int half = 0; half < 2; ++half) {
        float m0[NPT], m1[NPT], m2[NPT];
#pragma unroll
        for (int q = 0; q < NPT; ++q) { m0[q] = 1e30f; m1[q] = 1e30f; m2[q] = 1e30f; }
        int sb = half * SUBL;
#pragma unroll 8
        for (int s = sb; s < sb + SUBL; ++s) {
            v4f p = *(const v4f*)(smem + 4 * s);
            v2f pxy = __builtin_shufflevector(p, p, 0, 1);
            v2f pzw = __builtin_shufflevector(p, p, 2, 3);
            v2f eA, eB;
            E2_FROM(pxy, pzw, XXa, YYa, ZZa, eA);
            E2_FROM(pxy, pzw, XXb, YYb, ZZb, eB);
            ins_v(eA.x, m0[0], m1[0], m2[0]);
            ins_v(eA.y, m0[1], m1[1], m2[1]);
            ins_v(eB.x, m0[2], m1[2], m2[2]);
            ins_v(eB.y, m0[3], m1[3], m2[3]);
        }
        int sub = ch * 2 + half;
        size_t base = (size_t)(sub * BB + b) * 3;
#pragma unroll
        for (int q = 0; q < NPT; ++q) {
            int n = n0 + q * 256;
            pv[(base + 0) * NN + n] = m0[q];
            pv[(base + 1) * NN + n] = m1[q];
            pv[(base + 2) * NN + n] = m2[q];
        }
    }
}

// ---------------------------------------------------------------------------
// gemm phase: 64s x 128o tile, 4s x 8o micro: per cc 3 ds_read_b128 (a + 2bv)
// feed 16 pk_fma (LDS cy/pk_fma 1.5 -> 1.125). bv reads are 16-lane
// broadcasts (conflict-free). Accumulation order per output unchanged ->
// Gh bitwise identical.
// ---------------------------------------------------------------------------
__device__ __forceinline__ void gemm_phase(int g, int t, float* smem,
                                           const float* __restrict__ P,
                                           const float* __restrict__ W,
                                           const float* __restrict__ bias,
                                           unsigned short* __restrict__ Gh) {
    int o0 = (g & 1) * 128;
    int s0 = ((g >> 1) & 63) * 64;
    int b  = g >> 7;
    float* sP = smem;              // 16 x 64
    float* sW = smem + 1024;       // 16 x 132 (padded)
    int i = t & 15;
    int j = t >> 4;

    v2f acc2[4][4];                // 4 s x 8 o (4 v2f per row)
#pragma unroll
    for (int p = 0; p < 4; ++p)
#pragma unroll
        for (int q = 0; q < 4; ++q) acc2[p][q] = (v2f){0.f, 0.f};

    const float* Pb = P + (size_t)b * CIN * SS;

    for (int c0 = 0; c0 < CIN; c0 += 16) {
        __syncthreads();
        {
            int col = t & 63;
            int r0r = t >> 6;
#pragma unroll
            for (int r = 0; r < 4; ++r) {
                int row = r0r + r * 4;
                sP[row * 64 + col] = Pb[(size_t)(c0 + row) * SS + s0 + col];
            }
        }
        {
            int cc = t & 15;
            int obase = t >> 4;
#pragma unroll
            for (int r = 0; r < 8; ++r) {
                int oo = obase + 16 * r;
                sW[cc * 132 + oo] = W[(size_t)(o0 + oo) * CIN + c0 + cc];
            }
        }
        __syncthreads();

#pragma unroll
        for (int cc = 0; cc < 16; ++cc) {
            v4f a   = *(const v4f*)&sP[cc * 64 + i * 4];
            v4f bv0 = *(const v4f*)&sW[cc * 132 + j * 8];
            v4f bv1 = *(const v4f*)&sW[cc * 132 + j * 8 + 4];
            v2f a01 = __builtin_shufflevector(a, a, 0, 1);
            v2f a23 = __builtin_shufflevector(a, a, 2, 3);
            v2f b01 = __builtin_shufflevector(bv0, bv0, 0, 1);
            v2f b23 = __builtin_shufflevector(bv0, bv0, 2, 3);
            v2f b45 = __builtin_shufflevector(bv1, bv1, 0, 1);
            v2f b67 = __builtin_shufflevector(bv1, bv1, 2, 3);
            PK_LO(acc2[0][0], a01, b01); PK_LO(acc2[0][1], a01, b23);
            PK_LO(acc2[0][2], a01, b45); PK_LO(acc2[0][3], a01, b67);  // a.x
            PK_HI(acc2[1][0], a01, b01); PK_HI(acc2[1][1], a01, b23);
            PK_HI(acc2[1][2], a01, b45); PK_HI(acc2[1][3], a01, b67);  // a.y
            PK_LO(acc2[2][0], a23, b01); PK_LO(acc2[2][1], a23, b23);
            PK_LO(acc2[2][2], a23, b45); PK_LO(acc2[2][3], a23, b67);  // a.z
            PK_HI(acc2[3][0], a23, b01); PK_HI(acc2[3][1], a23, b23);
            PK_HI(acc2[3][2], a23, b45); PK_HI(acc2[3][3], a23, b67);  // a.w
        }
    }

    float bb[8];
#pragma unroll
    for (int q = 0; q < 8; ++q) bb[q] = bias[o0 + j * 8 + q];
#pragma unroll
    for (int p = 0; p < 4; ++p) {
        ushort4 v0, v1;
        v0.x = f2bf(acc2[p][0].x + bb[0]);
        v0.y = f2bf(acc2[p][0].y + bb[1]);
        v0.z = f2bf(acc2[p][1].x + bb[2]);
        v0.w = f2bf(acc2[p][1].y + bb[3]);
        v1.x = f2bf(acc2[p][2].x + bb[4]);
        v1.y = f2bf(acc2[p][2].y + bb[5]);
        v1.z = f2bf(acc2[p][3].x + bb[6]);
        v1.w = f2bf(acc2[p][3].y + bb[7]);
        size_t off = ((size_t)b * SS + s0 + i * 4 + p) * COUT + o0 + j * 8;
        *(ushort4*)&Gh[off]     = v0;
        *(ushort4*)&Gh[off + 4] = v1;
    }
}

// ---------------------------------------------------------------------------
__global__ __launch_bounds__(256) void k_fused(const float* __restrict__ xyz1,
                                               const float* __restrict__ xyz2,
                                               const float* __restrict__ P,
                                               const float* __restrict__ W,
                                               const float* __restrict__ bias,
                                               unsigned short* __restrict__ Gh,
                                               float* __restrict__ pv,
                                               float4* __restrict__ cand4) {
    __shared__ float smem[3136];   // 12.25 KB: knn 512 float4 / gemm sP+sW
    int bid = blockIdx.x;
    int t   = threadIdx.x;

    if (bid < KNNB) {
        knn_phase(bid, t, smem, xyz1, xyz2, pv, cand4);
    } else {
        gemm_phase(bid - KNNB, t, smem, P, W, bias, Gh);
    }
}

// ---------------------------------------------------------------------------
// Resolve v6 (unchanged from round 9): phase A coalesced fold; phase B
// wave-per-query scan with batched sub-loads; finalist rank-compact +
// lex-insert. Proven passing.
// ---------------------------------------------------------------------------
__global__ __launch_bounds__(256) void k_resolve(const float* __restrict__ pv,
                                                 const float* __restrict__ xyz1,
                                                 const float4* __restrict__ cand4,
                                                 float4* __restrict__ wi4,
                                                 int4* __restrict__ gi4) {
    __shared__ float    sv[4][64][3];   // per-wave partial triples
    __shared__ float    sj0[16][64];    // per-(sub,query) sub-min values
    __shared__ float    sm2[64];        // per-query exact 3rd-smallest
    __shared__ unsigned smask[64];      // per-query winning-sub mask
    __shared__ float    sq[64][4];      // per-query {xm2c, ym2c, zm2c, nrm}
    __shared__ uint2    sl[4][16];      // per-wave finalist slots
    int bid = blockIdx.x;
    int b   = bid >> 8;                 // 256 blocks per batch
    int n0  = (bid & 255) * 64;
    int t   = threadIdx.x;
    int w   = t >> 6;
    int l   = t & 63;

    const float* xb = xyz1 + (size_t)b * 3 * NN;

    // ---- phase A: coalesced fold of 12 planes per wave ----
    {
        float a0 = 1e30f, a1 = 1e30f, a2 = 1e30f;
#pragma unroll
        for (int i = 0; i < 12; ++i) {
            int sub = w * 4 + i / 3;    // i/3, i%3 compile-time per iteration
            int j   = i % 3;
            float v = pv[((size_t)(sub * BB + b) * 3 + j) * NN + n0 + l];
            if (j == 0) sj0[sub][l] = v;
            ins_v(v, a0, a1, a2);
        }
        sv[w][l][0] = a0; sv[w][l][1] = a1; sv[w][l][2] = a2;
    }
    if (w == 1) {                       // stage query coords (coalesced)
        float qx = xb[n0 + l], qy = xb[NN + n0 + l], qz = xb[2 * NN + n0 + l];
        sq[l][0] = -2.0f * qx;
        sq[l][1] = -2.0f * qy;
        sq[l][2] = -2.0f * qz;
        sq[l][3] = fmaf(qx, qx, fmaf(qy, qy, qz * qz));
    }
    __syncthreads();

    // ---- per-query final fold + screen (all waves redundantly) ----
    {
        float m0 = 1e30f, m1 = 1e30f, m2 = 1e30f;
#pragma unroll
        for (int ww = 0; ww < 4; ++ww) {
            ins_v(sv[ww][l][0], m0, m1, m2);
            ins_v(sv[ww][l][1], m0, m1, m2);
            ins_v(sv[ww][l][2], m0, m1, m2);
        }
        unsigned mk = 0;
#pragma unroll
        for (int sub = 0; sub < SUBS; ++sub)
            mk |= (sj0[sub][l] <= m2) ? (1u << sub) : 0u;
        if (w == 0) { sm2[l] = m2; smask[l] = mk; }
    }
    __syncthreads();

    // ---- phase B: wave-per-query scan, batched sub-loads ----
    const float4* cb = cand4 + (size_t)b * SS;
    for (int qq = 0; qq < 16; ++qq) {
        int q = w * 16 + qq;
        int n = n0 + q;
        float    m2q = sm2[q];          // broadcast LDS reads
        unsigned mm  = smask[q];
        float xm2c = sq[q][0], ym2c = sq[q][1], zm2c = sq[q][2];

        int cntw = __popc(mm);          // wave-uniform, >=1 always
        unsigned r1m = mm  & (mm  - 1);
        unsigned r2m = r1m & (r1m - 1);
        int su0 = __builtin_ctz(mm);
        int su1 = r1m ? __builtin_ctz(r1m) : su0;
        int su2 = r2m ? __builtin_ctz(r2m) : su0;

        // issue ALL loads before any insert (single latency exposure)
        float4 P0[4], P1[4], P2[4];
#pragma unroll
        for (int r = 0; r < 4; ++r) P0[r] = cb[su0 * SUBL + r * 64 + l];
#pragma unroll
        for (int r = 0; r < 4; ++r) P1[r] = cb[su1 * SUBL + r * 64 + l];
#pragma unroll
        for (int r = 0; r < 4; ++r) P2[r] = cb[su2 * SUBL + r * 64 + l];

        float k0 = 1e30f, k1 = 1e30f, k2 = 1e30f;
        int   i0 = 0,     i1 = 0,     i2 = 0;
#pragma unroll
        for (int r = 0; r < 4; ++r) {   // sub su0: always
            int gi = su0 * SUBL + r * 64 + l;
            float e = fmaf(P0[r].x, xm2c,
                      fmaf(P0[r].y, ym2c, fmaf(P0[r].z, zm2c, P0[r].w)));
            insert_vi(e, gi, k0, k1, k2, i0, i1, i2);
        }
        if (cntw > 1) {
#pragma unroll
            for (int r = 0; r < 4; ++r) {
                int gi = su1 * SUBL + r * 64 + l;
                float e = fmaf(P1[r].x, xm2c,
                          fmaf(P1[r].y, ym2c, fmaf(P1[r].z, zm2c, P1[r].w)));
                insert_vi(e, gi, k0, k1, k2, i0, i1, i2);
            }
        }
        if (cntw > 2) {
#pragma unroll
            for (int r = 0; r < 4; ++r) {
                int gi = su2 * SUBL + r * 64 + l;
                float e = fmaf(P2[r].x, xm2c,
                          fmaf(P2[r].y, ym2c, fmaf(P2[r].z, zm2c, P2[r].w)));
                insert_vi(e, gi, k0, k1, k2, i0, i1, i2);
            }
        }
        if (cntw > 3) {                 // rare remainder, subs > su2 ascending
            unsigned msc = r2m & (r2m - 1);
            while (msc) {
                int sub = __builtin_ctz(msc); msc &= msc - 1;
                int sb = sub * SUBL;
#pragma unroll
                for (int r = 0; r < 4; ++r) {
                    int gi = sb + r * 64 + l;
                    float4 p = cb[gi];
                    float e = fmaf(p.x, xm2c,
                              fmaf(p.y, ym2c, fmaf(p.z, zm2c, p.w)));
                    insert_vi(e, gi, k0, k1, k2, i0, i1, i2);
                }
            }
        }

        unsigned long long b0 = __ballot(k0 <= m2q);
        unsigned long long b1 = __ballot(k1 <= m2q);
        unsigned long long b2 = __ballot(k2 <= m2q);
        int p0 = __popcll(b0), p1 = __popcll(b1);
        int cnt3 = p0 + p1 + __popcll(b2);
        float K0 = 1e30f, K1 = 1e30f, K2 = 1e30f;
        int   I0 = 0,     I1 = 0,     I2 = 0;
        if (cnt3 <= 16) {
            if (k0 <= m2q) sl[w][ltc(b0)]           = make_uint2(__float_as_uint(k0), (unsigned)i0);
            if (k1 <= m2q) sl[w][p0 + ltc(b1)]      = make_uint2(__float_as_uint(k1), (unsigned)i1);
            if (k2 <= m2q) sl[w][p0 + p1 + ltc(b2)] = make_uint2(__float_as_uint(k2), (unsigned)i2);
            // same-wave LDS RAW: compiler inserts lgkmcnt wait, no barrier
            for (int j = 0; j < cnt3; ++j) {
                uint2 u = sl[w][j];
                ins_lex(__uint_as_float(u.x), (int)u.y, K0, K1, K2, I0, I1, I2);
            }
        } else {       // mass-tie pathology: exact serial rescan (broadcast)
            unsigned mf = mm;
            while (mf) {
                int sub = __builtin_ctz(mf); mf &= mf - 1;
                int sb = sub * SUBL;
                for (int s = 0; s < SUBL; ++s) {
                    float4 p = cb[sb + s];
                    float e = fmaf(p.x, xm2c, fmaf(p.y, ym2c, fmaf(p.z, zm2c, p.w)));
                    ins_lex(e, sb + s, K0, K1, K2, I0, I1, I2);
                }
            }
        }

        if (l == 0) {
            float nrm = sq[q][3];
            float d0 = K0 + nrm, d1 = K1 + nrm, d2 = K2 + nrm;
            float r0 = 1.0f / (d0 + 1e-8f);
            float r1 = 1.0f / (d1 + 1e-8f);
            float r2 = 1.0f / (d2 + 1e-8f);
            float inv = 1.0f / (r0 + r1 + r2);
            size_t oq = (size_t)b * NN + n;
            wi4[oq] = make_float4(r0 * inv, r1 * inv, r2 * inv, 0.f);
            gi4[oq] = make_int4(I0, I1, I2, 0);
        }
    }
}

// ---------------------------------------------------------------------------
// Output: unchanged (XCD-swizzled flat grid, 64q x 64ch blocks,
// 4-query/wave MLP gather, stride-68 tile, coalesced stores).
// ---------------------------------------------------------------------------
__global__ __launch_bounds__(256) void k_out(const unsigned short* __restrict__ Gh,
                                             const float4* __restrict__ wi4,
                                             const int4* __restrict__ gi4,
                                             float* __restrict__ out) {
    __shared__ float  tile[64 * 68];   // 17.4 KB
    __shared__ float4 swv[64];
    __shared__ int4   siv[64];
    int bid  = blockIdx.x;
    int x    = bid & 7;                // XCD slot (blockIdx % 8 round-robin)
    int b    = x >> 1;                 // 2 XCDs per batch
    int local = (bid >> 3) + (x & 1) * 512;   // 0..1023 per batch
    int nb   = local & 255;            // 256 n-blocks
    int oc   = local >> 8;             // 4 o-chunks
    int n0   = nb * 64;
    int o0   = oc * 64;
    int t    = threadIdx.x;
    int wave = t >> 6;
    int lane = t & 63;
    int qg   = lane >> 4;     // query-in-group 0..3
    int c16  = lane & 15;     // channel quad 0..15

    if (t < 64) {
        size_t q = (size_t)b * NN + n0 + t;
        swv[t] = wi4[q];
        siv[t] = gi4[q];
    }
    __syncthreads();

    const unsigned short* Gb = Gh + (size_t)b * SS * COUT;

#pragma unroll
    for (int pass = 0; pass < 4; ++pass) {
        int q = pass * 16 + wave * 4 + qg;
        float4 wv = swv[q];
        int4   iv = siv[q];
        int co = o0 + c16 * 4;
        ushort4 a0 = *(const ushort4*)(Gb + (size_t)iv.x * COUT + co);
        ushort4 a1 = *(const ushort4*)(Gb + (size_t)iv.y * COUT + co);
        ushort4 a2 = *(const ushort4*)(Gb + (size_t)iv.z * COUT + co);
        float4 v;
        v.x = fmaf(wv.x, bf2f(a0.x), fmaf(wv.y, bf2f(a1.x), wv.z * bf2f(a2.x)));
        v.y = fmaf(wv.x, bf2f(a0.y), fmaf(wv.y, bf2f(a1.y), wv.z * bf2f(a2.y)));
        v.z = fmaf(wv.x, bf2f(a0.z), fmaf(wv.y, bf2f(a1.z), wv.z * bf2f(a2.z)));
        v.w = fmaf(wv.x, bf2f(a0.w), fmaf(wv.y, bf2f(a1.w), wv.z * bf2f(a2.w)));
        *(float4*)&tile[q * 68 + c16 * 4] = v;
    }
    __syncthreads();

    float* obase = out + ((size_t)b * COUT + o0) * NN + n0 + lane;
#pragma unroll
    for (int g = 0; g < 4; ++g) {
        int c = wave * 16 + g * 4;
        float4 v = *(const float4*)&tile[lane * 68 + c];
        obase[(size_t)(c + 0) * NN] = v.x;
        obase[(size_t)(c + 1) * NN] = v.y;
        obase[(size_t)(c + 2) * NN] = v.z;
        obase[(size_t)(c + 3) * NN] = v.w;
    }
}

// ---------------------------------------------------------------------------
extern "C" void kernel_launch(void* const* d_in, const int* in_sizes, int n_in,
                              void* d_out, int out_size, void* d_ws, size_t ws_size,
                              hipStream_t stream) {
    const float* xyz1    = (const float*)d_in[0];   // [B,3,N]
    const float* xyz2    = (const float*)d_in[1];   // [B,3,S]
    const float* points2 = (const float*)d_in[2];   // [B,CIN,S]
    const float* W       = (const float*)d_in[3];   // [COUT,CIN]
    const float* bias    = (const float*)d_in[4];   // [COUT]
    float* out = (float*)d_out;                     // [B,COUT,N]

    char* ws = (char*)d_ws;
    // workspace layout (bytes), total 23,068,672 (proven size, unchanged):
    //   pv  : 0        .. 12,582,912  ([SUBS=16][B][3][N] f32 sub top-3 values)
    //   Gh  : 12582912 .. 20,971,520  ([B][S][COUT] bf16)
    //   wi4 : 20971520 .. 22,020,096  ([B][N] float4)
    //   gi4 : 22020096 .. 23,068,672  ([B][N] int4)
    float*          pv  = (float*)(ws);
    unsigned short* Gh  = (unsigned short*)(ws + 12582912);
    float4*         wi4 = (float4*)(ws + 20971520);
    int4*           gi4 = (int4*)(ws + 22020096);
    // cand4 ([B][S] float4 = 256 KB) lives in the TAIL of `out`:
    // written by k_fused, read by k_resolve, overwritten by k_out (stream-
    // ordered). out = 67,108,864 B; tail offset = 67,108,864 - 262,144.
    float4* cand4 = (float4*)((char*)d_out + 66846720);

    k_fused<<<dim3(KNNB + GEMMB), 256, 0, stream>>>(xyz1, xyz2, points2, W, bias,
                                                    Gh, pv, cand4);
    k_resolve<<<dim3(RSLVB), 256, 0, stream>>>(pv, xyz1, cand4, wi4, gi4);
    k_out<<<dim3(4096), 256, 0, stream>>>(Gh, wi4, gi4, out);
}

// Round 11
// 204.008 us; speedup vs baseline: 1.0330x; 1.0330x over previous
//
#include <hip/hip_runtime.h>

#define BB 4
#define NN 16384
#define SS 4096
#define CIN 256
#define COUT 256

#define SC 8                  // s-chunks per knn block pass
#define SCS (SS / SC)         // 512 candidates staged per knn block
#define SUBS 16               // coarse subs (256 cands) for exact-m2 triples
#define SUBL 256
#define FSUB 64               // fine subs (64 cands) for the re-scan screen
#define KNNB ((NN / 512) * SC * BB)           // 32*8*4 = 1024 knn blocks (NPT=2)
#define GEMMB ((COUT / 64) * (SS / 64) * BB)  // 4*64*4 = 1024 gemm blocks
#define RSLVB (BB * NN / 64)                  // 1024 resolve blocks (64 q each)
// grid = 2048 = 8 blocks/CU (round-9 proven best for k_fused; round-10's
// 4-block/CU config regressed -> reverted).

typedef float v2f __attribute__((ext_vector_type(2)));
typedef float v4f __attribute__((ext_vector_type(4)));

__device__ __forceinline__ unsigned short f2bf(float f) {   // RNE float->bf16
    unsigned u = __float_as_uint(f);
    u += 0x7FFF + ((u >> 16) & 1);
    return (unsigned short)(u >> 16);
}
__device__ __forceinline__ float bf2f(unsigned short h) {
    return __uint_as_float((unsigned)h << 16);
}

// Value-only exact top-3 insert (sorted invariant a<=b<=c): 3 full-rate ops.
__device__ __forceinline__ void ins_v(float e, float& a, float& b, float& c) {
    float n1 = __builtin_amdgcn_fmed3f(e, a, b);
    float n2 = __builtin_amdgcn_fmed3f(e, b, c);
    a = fminf(a, e); b = n1; c = n2;
}

// Exact stable top-3 insert, value + index, strict '<' (requires ascending-
// index processing order). Proven passing rounds 3/5-10.
__device__ __forceinline__ void insert_vi(float e, int gi,
                                          float& k0, float& k1, float& k2,
                                          int& i0, int& i1, int& i2) {
    bool c0 = e < k0, c1 = e < k1, c2 = e < k2;
    float n0 = fminf(e, k0);
    float n1 = __builtin_amdgcn_fmed3f(e, k0, k1);
    float n2 = __builtin_amdgcn_fmed3f(e, k1, k2);
    int t1 = c0 ? i0 : gi;
    int t2 = c1 ? i1 : gi;
    i0 = c0 ? gi : i0;
    i1 = c1 ? t1 : i1;
    i2 = c2 ? t2 : i2;
    k0 = n0; k1 = n1; k2 = n2;
}

// Lexicographic (value, index) insert: order-independent exact stable top-3.
// Used only on the <=16 gathered finalists per query. Proven rounds 7-10.
__device__ __forceinline__ void ins_lex(float e, int gi,
                                        float& k0, float& k1, float& k2,
                                        int& i0, int& i1, int& i2) {
    bool c0 = (e < k0) || (e == k0 && gi < i0);
    bool c1 = (e < k1) || (e == k1 && gi < i1);
    bool c2 = (e < k2) || (e == k2 && gi < i2);
    float n0 = fminf(e, k0);
    float n1 = __builtin_amdgcn_fmed3f(e, k0, k1);
    float n2 = __builtin_amdgcn_fmed3f(e, k1, k2);
    int t1 = c0 ? i0 : gi;
    int t2 = c1 ? i1 : gi;
    i0 = c0 ? gi : i0;
    i1 = c1 ? t1 : i1;
    i2 = c2 ? t2 : i2;
    k0 = n0; k1 = n1; k2 = n2;
}

// popcount of mask bits strictly below this lane
__device__ __forceinline__ int ltc(unsigned long long m) {
    return __builtin_amdgcn_mbcnt_hi(
        (unsigned)(m >> 32), __builtin_amdgcn_mbcnt_lo((unsigned)m, 0));
}

// v_pk_fma_f32 packed distance: lo/hi = two queries; candidate coords
// broadcast via op_sel. IEEE f32 fma per half, z->y->x nesting:
//   e = x*X + (y*Y + (z*Z + w))
#define E2_FROM(p_xy, p_zw, XX, YY, ZZ, e2)                                    \
    do {                                                                       \
        asm("v_pk_fma_f32 %0, %1, %2, %3 op_sel:[0,0,1] op_sel_hi:[0,1,1]"     \
            : "=v"(e2) : "v"(p_zw), "v"(ZZ), "v"(p_zw));                       \
        asm("v_pk_fma_f32 %0, %1, %2, %0 op_sel:[1,0,0] op_sel_hi:[1,1,1]"     \
            : "+v"(e2) : "v"(p_xy), "v"(YY));                                  \
        asm("v_pk_fma_f32 %0, %1, %2, %0 op_sel:[0,0,0] op_sel_hi:[0,1,1]"     \
            : "+v"(e2) : "v"(p_xy), "v"(XX));                                  \
    } while (0)

#define PK_LO(acc, ap, bw)                                                     \
    asm("v_pk_fma_f32 %0, %1, %2, %0 op_sel:[0,0,0] op_sel_hi:[0,1,1]"         \
        : "+v"(acc) : "v"(ap), "v"(bw))
#define PK_HI(acc, ap, bw)                                                     \
    asm("v_pk_fma_f32 %0, %1, %2, %0 op_sel:[1,0,0] op_sel_hi:[1,1,1]"         \
        : "+v"(acc) : "v"(ap), "v"(bw))

// ---------------------------------------------------------------------------
// knn phase (NPT=2, round-9 proven structure): value-only exact top-3 per
// 256-sub (pv, unchanged bitwise) PLUS per-64-group exact min (pm) for the
// resolve fine screen (+1 fminf/query/cand, 8 extra coalesced stores).
// nb==0 blocks dump the staged chunk to cand4.
// ---------------------------------------------------------------------------
__device__ __forceinline__ void knn_phase(int id, int t, float* smem,
                                          const float* __restrict__ xyz1,
                                          const float* __restrict__ xyz2,
                                          float* __restrict__ pv,
                                          float* __restrict__ pm,
                                          float4* __restrict__ cand4) {
    int nb = id & 31;
    int ch = (id >> 5) & 7;
    int b  = id >> 8;
    int s0 = ch * SCS;

    float4* smv = (float4*)smem;
    const float* x2 = xyz2 + (size_t)b * 3 * SS;
    for (int i = t; i < SCS; i += 256) {
        float px = x2[s0 + i];
        float py = x2[SS + s0 + i];
        float pz = x2[2 * SS + s0 + i];
        float4 p4 = make_float4(px, py, pz, fmaf(px, px, fmaf(py, py, pz * pz)));
        smv[i] = p4;
        if (nb == 0) cand4[(size_t)b * SS + s0 + i] = p4;   // 32 dump blocks
    }
    __syncthreads();

    int n0  = nb * 512 + t;
    int n1q = n0 + 256;
    const float* xb = xyz1 + (size_t)b * 3 * NN;
    float ax = xb[n0],  ay = xb[NN + n0],  az = xb[2 * NN + n0];
    float bx = xb[n1q], by = xb[NN + n1q], bz = xb[2 * NN + n1q];
    v2f XX = {-2.0f * ax, -2.0f * bx};
    v2f YY = {-2.0f * ay, -2.0f * by};
    v2f ZZ = {-2.0f * az, -2.0f * bz};

#pragma unroll
    for (int half = 0; half < 2; ++half) {
        float A0 = 1e30f, A1 = 1e30f, A2 = 1e30f;
        float B0 = 1e30f, B1 = 1e30f, B2 = 1e30f;
        int sb = half * SUBL;
#pragma unroll
        for (int k64 = 0; k64 < 4; ++k64) {
            float mA = 1e30f, mB = 1e30f;
#pragma unroll 8
            for (int s2 = 0; s2 < 64; ++s2) {
                int s = sb + k64 * 64 + s2;
                v4f p = *(const v4f*)(smem + 4 * s);
                v2f pxy = __builtin_shufflevector(p, p, 0, 1);
                v2f pzw = __builtin_shufflevector(p, p, 2, 3);
                v2f e2;
                E2_FROM(pxy, pzw, XX, YY, ZZ, e2);
                ins_v(e2.x, A0, A1, A2);
                ins_v(e2.y, B0, B1, B2);
                mA = fminf(mA, e2.x);
                mB = fminf(mB, e2.y);
            }
            int sub64 = ch * 8 + half * 4 + k64;
            size_t pb = (size_t)(sub64 * BB + b) * NN;
            pm[pb + n0]  = mA;
            pm[pb + n1q] = mB;
        }
        int sub = ch * 2 + half;
        size_t base = (size_t)(sub * BB + b) * 3;
        pv[(base + 0) * NN + n0]  = A0;
        pv[(base + 1) * NN + n0]  = A1;
        pv[(base + 2) * NN + n0]  = A2;
        pv[(base + 0) * NN + n1q] = B0;
        pv[(base + 1) * NN + n1q] = B1;
        pv[(base + 2) * NN + n1q] = B2;
    }
}

// ---------------------------------------------------------------------------
// gemm phase: 64s x 64o tile, 4x4 micro via 8 v_pk_fma_f32 per cc
// (round-9 proven, unchanged).
// ---------------------------------------------------------------------------
__device__ __forceinline__ void gemm_phase(int g, int t, float* smem,
                                           const float* __restrict__ P,
                                           const float* __restrict__ W,
                                           const float* __restrict__ bias,
                                           unsigned short* __restrict__ Gh) {
    int o0 = (g & 3) * 64;
    int s0 = ((g >> 2) & 63) * 64;
    int b  = g >> 8;
    float* sP = smem;              // 16 x 64
    float* sW = smem + 1024;       // 16 x 68 (padded)
    int i = t & 15;
    int j = t >> 4;

    v2f acc2[4][2];
#pragma unroll
    for (int p = 0; p < 4; ++p) {
        acc2[p][0] = (v2f){0.f, 0.f};
        acc2[p][1] = (v2f){0.f, 0.f};
    }

    const float* Pb = P + (size_t)b * CIN * SS;

    for (int c0 = 0; c0 < CIN; c0 += 16) {
        __syncthreads();
        {
            int col = t & 63;
            int r0r = t >> 6;
#pragma unroll
            for (int r = 0; r < 4; ++r) {
                int row = r0r + r * 4;
                sP[row * 64 + col] = Pb[(size_t)(c0 + row) * SS + s0 + col];
            }
        }
        {
            int cc = t & 15;
            int obase = t >> 4;
#pragma unroll
            for (int r = 0; r < 4; ++r) {
                int oo = obase + 16 * r;
                sW[cc * 68 + oo] = W[(size_t)(o0 + oo) * CIN + c0 + cc];
            }
        }
        __syncthreads();

#pragma unroll
        for (int cc = 0; cc < 16; ++cc) {
            v4f a  = *(const v4f*)&sP[cc * 64 + i * 4];
            v4f bv = *(const v4f*)&sW[cc * 68 + j * 4];
            v2f a01 = __builtin_shufflevector(a, a, 0, 1);
            v2f a23 = __builtin_shufflevector(a, a, 2, 3);
            v2f b01 = __builtin_shufflevector(bv, bv, 0, 1);
            v2f b23 = __builtin_shufflevector(bv, bv, 2, 3);
            PK_LO(acc2[0][0], a01, b01); PK_LO(acc2[0][1], a01, b23);  // a.x
            PK_HI(acc2[1][0], a01, b01); PK_HI(acc2[1][1], a01, b23);  // a.y
            PK_LO(acc2[2][0], a23, b01); PK_LO(acc2[2][1], a23, b23);  // a.z
            PK_HI(acc2[3][0], a23, b01); PK_HI(acc2[3][1], a23, b23);  // a.w
        }
    }

    float b0 = bias[o0 + j * 4 + 0];
    float b1 = bias[o0 + j * 4 + 1];
    float b2 = bias[o0 + j * 4 + 2];
    float b3 = bias[o0 + j * 4 + 3];
#pragma unroll
    for (int p = 0; p < 4; ++p) {
        ushort4 v;
        v.x = f2bf(acc2[p][0].x + b0);
        v.y = f2bf(acc2[p][0].y + b1);
        v.z = f2bf(acc2[p][1].x + b2);
        v.w = f2bf(acc2[p][1].y + b3);
        size_t off = ((size_t)b * SS + s0 + i * 4 + p) * COUT + o0 + j * 4;
        *(ushort4*)&Gh[off] = v;
    }
}

// ---------------------------------------------------------------------------
__global__ __launch_bounds__(256) void k_fused(const float* __restrict__ xyz1,
                                               const float* __restrict__ xyz2,
                                               const float* __restrict__ P,
                                               const float* __restrict__ W,
                                               const float* __restrict__ bias,
                                               unsigned short* __restrict__ Gh,
                                               float* __restrict__ pv,
                                               float* __restrict__ pm,
                                               float4* __restrict__ cand4) {
    __shared__ float smem[2112];   // 8.25 KB: knn 512 float4 / gemm sP+sW
    int bid = blockIdx.x;
    int t   = threadIdx.x;

    if (bid < KNNB) {
        knn_phase(bid, t, smem, xyz1, xyz2, pv, pm, cand4);
    } else {
        gemm_phase(bid - KNNB, t, smem, P, W, bias, Gh);
    }
}

// ---------------------------------------------------------------------------
// Resolve v7 (fine 64-grain screen): per query the re-scan is 3 coalesced
// 1-KB loads + 3 insert_vi (one candidate per lane per fine sub) instead of
// 12 loads + 12 inserts over 256-subs -> ~4x less scan traffic (the v1-v6
// common bottleneck: ~800 MB of 256-cand re-scans).
//   A1: pv fold (12 coarse planes/wave, coalesced) -> partial triples in LDS.
//   A2: stage 64 fine sub-min planes into LDS (16/wave, coalesced).
//   m2: per-query combine (redundant per wave) -> exact 3rd-smallest; 64-bit
//       winning mask from the fine sub-mins (<=3 set generically, since only
//       subs containing a global-top-3 member can have min <= m2).
//   B:  per query (16/wave): ctz cascade -> su0<su1<su2; 3 coalesced loads;
//       exact strict-'<' insert_vi ascending; remainder loop if cntw>3;
//       finalists (<= m2) ballot/rank-compacted -> lex merge (proven v6).
//       cnt3>16 mass-tie -> broadcast serial rescan of winning subs.
// ---------------------------------------------------------------------------
__global__ __launch_bounds__(256) void k_resolve(const float* __restrict__ pv,
                                                 const float* __restrict__ pm,
                                                 const float* __restrict__ xyz1,
                                                 const float4* __restrict__ cand4,
                                                 float4* __restrict__ wi4,
                                                 int4* __restrict__ gi4) {
    __shared__ float    sv[4][64][3];     // per-wave partial triples
    __shared__ float    pmv[FSUB][65];    // fine sub-mins, padded (16.6 KB)
    __shared__ float    sm2[64];          // per-query exact 3rd-smallest
    __shared__ unsigned long long smask[64];
    __shared__ float    sq[64][4];        // {xm2c, ym2c, zm2c, nrm}
    __shared__ uint2    sl[4][16];        // per-wave finalist slots
    int bid = blockIdx.x;
    int b   = bid >> 8;                   // 256 blocks per batch
    int n0  = (bid & 255) * 64;
    int t   = threadIdx.x;
    int w   = t >> 6;
    int l   = t & 63;

    const float* xb = xyz1 + (size_t)b * 3 * NN;

    // ---- A1: coarse pv fold, 12 planes per wave (coalesced) ----
    {
        float a0 = 1e30f, a1 = 1e30f, a2 = 1e30f;
#pragma unroll
        for (int i = 0; i < 12; ++i) {
            int sub = w * 4 + i / 3;
            int j   = i % 3;
            float v = pv[((size_t)(sub * BB + b) * 3 + j) * NN + n0 + l];
            ins_v(v, a0, a1, a2);
        }
        sv[w][l][0] = a0; sv[w][l][1] = a1; sv[w][l][2] = a2;
    }
    // ---- A2: stage fine sub-mins, 16 planes per wave (coalesced) ----
#pragma unroll
    for (int i = 0; i < 16; ++i) {
        int sub = w * 16 + i;
        pmv[sub][l] = pm[(size_t)(sub * BB + b) * NN + n0 + l];
    }
    if (w == 1) {                         // stage query coords (coalesced)
        float qx = xb[n0 + l], qy = xb[NN + n0 + l], qz = xb[2 * NN + n0 + l];
        sq[l][0] = -2.0f * qx;
        sq[l][1] = -2.0f * qy;
        sq[l][2] = -2.0f * qz;
        sq[l][3] = fmaf(qx, qx, fmaf(qy, qy, qz * qz));
    }
    __syncthreads();

    // ---- per-query m2 + 64-bit fine mask (all waves redundantly) ----
    {
        float m0 = 1e30f, m1 = 1e30f, m2 = 1e30f;
#pragma unroll
        for (int ww = 0; ww < 4; ++ww) {
            ins_v(sv[ww][l][0], m0, m1, m2);
            ins_v(sv[ww][l][1], m0, m1, m2);
            ins_v(sv[ww][l][2], m0, m1, m2);
        }
        unsigned long long mk = 0;
#pragma unroll
        for (int sub = 0; sub < FSUB; ++sub)
            mk |= (pmv[sub][l] <= m2) ? (1ull << sub) : 0ull;
        if (w == 0) { sm2[l] = m2; smask[l] = mk; }
    }
    __syncthreads();

    // ---- phase B: wave-per-query, 16 queries per wave ----
    const float4* cb = cand4 + (size_t)b * SS;
    for (int qq = 0; qq < 16; ++qq) {
        int q = w * 16 + qq;
        int n = n0 + q;
        float m2q = sm2[q];
        unsigned long long mm = smask[q];
        float xm2c = sq[q][0], ym2c = sq[q][1], zm2c = sq[q][2];

        int cntw = __popcll(mm);          // wave-uniform, >=1 always
        unsigned long long r1m = mm  & (mm  - 1);
        unsigned long long r2m = r1m & (r1m - 1);
        int su0 = __builtin_ctzll(mm);
        int su1 = r1m ? __builtin_ctzll(r1m) : su0;
        int su2 = r2m ? __builtin_ctzll(r2m) : su0;

        // all loads issue before any insert (single latency exposure);
        // one candidate per lane per fine sub
        float4 P0 = cb[su0 * 64 + l];
        float4 P1 = cb[su1 * 64 + l];
        float4 P2 = cb[su2 * 64 + l];

        float k0 = 1e30f, k1 = 1e30f, k2 = 1e30f;
        int   i0 = 0,     i1 = 0,     i2 = 0;
        {
            float e = fmaf(P0.x, xm2c, fmaf(P0.y, ym2c, fmaf(P0.z, zm2c, P0.w)));
            insert_vi(e, su0 * 64 + l, k0, k1, k2, i0, i1, i2);
        }
        if (cntw > 1) {
            float e = fmaf(P1.x, xm2c, fmaf(P1.y, ym2c, fmaf(P1.z, zm2c, P1.w)));
            insert_vi(e, su1 * 64 + l, k0, k1, k2, i0, i1, i2);
        }
        if (cntw > 2) {
            float e = fmaf(P2.x, xm2c, fmaf(P2.y, ym2c, fmaf(P2.z, zm2c, P2.w)));
            insert_vi(e, su2 * 64 + l, k0, k1, k2, i0, i1, i2);
        }
        if (cntw > 3) {                   // rare: extra subs, still ascending
            unsigned long long msc = r2m & (r2m - 1);
            while (msc) {
                int sub = __builtin_ctzll(msc); msc &= msc - 1;
                float4 p = cb[sub * 64 + l];
                float e = fmaf(p.x, xm2c, fmaf(p.y, ym2c, fmaf(p.z, zm2c, p.w)));
                insert_vi(e, sub * 64 + l, k0, k1, k2, i0, i1, i2);
            }
        }

        unsigned long long b0 = __ballot(k0 <= m2q);
        unsigned long long b1 = __ballot(k1 <= m2q);
        unsigned long long b2 = __ballot(k2 <= m2q);
        int p0 = __popcll(b0), p1 = __popcll(b1);
        int cnt3 = p0 + p1 + __popcll(b2);
        float K0 = 1e30f, K1 = 1e30f, K2 = 1e30f;
        int   I0 = 0,     I1 = 0,     I2 = 0;
        if (cnt3 <= 16) {
            if (k0 <= m2q) sl[w][ltc(b0)]           = make_uint2(__float_as_uint(k0), (unsigned)i0);
            if (k1 <= m2q) sl[w][p0 + ltc(b1)]      = make_uint2(__float_as_uint(k1), (unsigned)i1);
            if (k2 <= m2q) sl[w][p0 + p1 + ltc(b2)] = make_uint2(__float_as_uint(k2), (unsigned)i2);
            // same-wave LDS RAW: compiler inserts lgkmcnt wait, no barrier
            for (int j = 0; j < cnt3; ++j) {
                uint2 u = sl[w][j];
                ins_lex(__uint_as_float(u.x), (int)u.y, K0, K1, K2, I0, I1, I2);
            }
        } else {       // mass-tie pathology: exact serial rescan (broadcast)
            unsigned long long mf = mm;
            while (mf) {
                int sub = __builtin_ctzll(mf); mf &= mf - 1;
                for (int s = 0; s < 64; ++s) {
                    float4 p = cb[sub * 64 + s];
                    float e = fmaf(p.x, xm2c, fmaf(p.y, ym2c, fmaf(p.z, zm2c, p.w)));
                    ins_lex(e, sub * 64 + s, K0, K1, K2, I0, I1, I2);
                }
            }
        }

        if (l == 0) {
            float nrm = sq[q][3];
            float d0 = K0 + nrm, d1 = K1 + nrm, d2 = K2 + nrm;
            float r0 = 1.0f / (d0 + 1e-8f);
            float r1 = 1.0f / (d1 + 1e-8f);
            float r2 = 1.0f / (d2 + 1e-8f);
            float inv = 1.0f / (r0 + r1 + r2);
            size_t oq = (size_t)b * NN + n;
            wi4[oq] = make_float4(r0 * inv, r1 * inv, r2 * inv, 0.f);
            gi4[oq] = make_int4(I0, I1, I2, 0);
        }
    }
}

// ---------------------------------------------------------------------------
// Output: unchanged (XCD-swizzled flat grid, 64q x 64ch blocks,
// 4-query/wave MLP gather, stride-68 tile, coalesced stores).
// ---------------------------------------------------------------------------
__global__ __launch_bounds__(256) void k_out(const unsigned short* __restrict__ Gh,
                                             const float4* __restrict__ wi4,
                                             const int4* __restrict__ gi4,
                                             float* __restrict__ out) {
    __shared__ float  tile[64 * 68];   // 17.4 KB
    __shared__ float4 swv[64];
    __shared__ int4   siv[64];
    int bid  = blockIdx.x;
    int x    = bid & 7;                // XCD slot (blockIdx % 8 round-robin)
    int b    = x >> 1;                 // 2 XCDs per batch
    int local = (bid >> 3) + (x & 1) * 512;   // 0..1023 per batch
    int nb   = local & 255;            // 256 n-blocks
    int oc   = local >> 8;             // 4 o-chunks
    int n0   = nb * 64;
    int o0   = oc * 64;
    int t    = threadIdx.x;
    int wave = t >> 6;
    int lane = t & 63;
    int qg   = lane >> 4;     // query-in-group 0..3
    int c16  = lane & 15;     // channel quad 0..15

    if (t < 64) {
        size_t q = (size_t)b * NN + n0 + t;
        swv[t] = wi4[q];
        siv[t] = gi4[q];
    }
    __syncthreads();

    const unsigned short* Gb = Gh + (size_t)b * SS * COUT;

#pragma unroll
    for (int pass = 0; pass < 4; ++pass) {
        int q = pass * 16 + wave * 4 + qg;
        float4 wv = swv[q];
        int4   iv = siv[q];
        int co = o0 + c16 * 4;
        ushort4 a0 = *(const ushort4*)(Gb + (size_t)iv.x * COUT + co);
        ushort4 a1 = *(const ushort4*)(Gb + (size_t)iv.y * COUT + co);
        ushort4 a2 = *(const ushort4*)(Gb + (size_t)iv.z * COUT + co);
        float4 v;
        v.x = fmaf(wv.x, bf2f(a0.x), fmaf(wv.y, bf2f(a1.x), wv.z * bf2f(a2.x)));
        v.y = fmaf(wv.x, bf2f(a0.y), fmaf(wv.y, bf2f(a1.y), wv.z * bf2f(a2.y)));
        v.z = fmaf(wv.x, bf2f(a0.z), fmaf(wv.y, bf2f(a1.z), wv.z * bf2f(a2.z)));
        v.w = fmaf(wv.x, bf2f(a0.w), fmaf(wv.y, bf2f(a1.w), wv.z * bf2f(a2.w)));
        *(float4*)&tile[q * 68 + c16 * 4] = v;
    }
    __syncthreads();

    float* obase = out + ((size_t)b * COUT + o0) * NN + n0 + lane;
#pragma unroll
    for (int g = 0; g < 4; ++g) {
        int c = wave * 16 + g * 4;
        float4 v = *(const float4*)&tile[lane * 68 + c];
        obase[(size_t)(c + 0) * NN] = v.x;
        obase[(size_t)(c + 1) * NN] = v.y;
        obase[(size_t)(c + 2) * NN] = v.z;
        obase[(size_t)(c + 3) * NN] = v.w;
    }
}

// ---------------------------------------------------------------------------
extern "C" void kernel_launch(void* const* d_in, const int* in_sizes, int n_in,
                              void* d_out, int out_size, void* d_ws, size_t ws_size,
                              hipStream_t stream) {
    const float* xyz1    = (const float*)d_in[0];   // [B,3,N]
    const float* xyz2    = (const float*)d_in[1];   // [B,3,S]
    const float* points2 = (const float*)d_in[2];   // [B,CIN,S]
    const float* W       = (const float*)d_in[3];   // [COUT,CIN]
    const float* bias    = (const float*)d_in[4];   // [COUT]
    float* out = (float*)d_out;                     // [B,COUT,N]

    char* ws = (char*)d_ws;
    // workspace layout (bytes), total 23,068,672 (proven size, unchanged):
    //   pv  : 0        .. 12,582,912  ([SUBS=16][B][3][N] f32 sub top-3 values)
    //   Gh  : 12582912 .. 20,971,520  ([B][S][COUT] bf16)
    //   wi4 : 20971520 .. 22,020,096  ([B][N] float4)
    //   gi4 : 22020096 .. 23,068,672  ([B][N] int4)
    float*          pv  = (float*)(ws);
    unsigned short* Gh  = (unsigned short*)(ws + 12582912);
    float4*         wi4 = (float4*)(ws + 20971520);
    int4*           gi4 = (int4*)(ws + 22020096);
    // out-tail scratch (out = 67,108,864 B; written by k_fused, read by
    // k_resolve, overwritten by k_out -- stream-ordered):
    //   pm    : out + 50,069,504 .. 66,846,720  ([FSUB=64][B][N] f32 fine mins)
    //   cand4 : out + 66,846,720 .. 67,108,864  ([B][S] float4)
    float*  pm    = (float*)((char*)d_out + 50069504);
    float4* cand4 = (float4*)((char*)d_out + 66846720);

    k_fused<<<dim3(KNNB + GEMMB), 256, 0, stream>>>(xyz1, xyz2, points2, W, bias,
                                                    Gh, pv, pm, cand4);
    k_resolve<<<dim3(RSLVB), 256, 0, stream>>>(pv, pm, xyz1, cand4, wi4, gi4);
    k_out<<<dim3(4096), 256, 0, stream>>>(Gh, wi4, gi4, out);
}